// Round 11
// baseline (41.194 us; speedup 1.0000x reference)
//
#include <hip/hip_runtime.h>

#define HH   48
#define WW   96
#define CC   256
#define RRAD 4
#define DD   9
#define DD2  81
#define PP   10
#define HWSZ (HH * WW)              // 4608
#define ROWB 512                    // bytes per bf16 channel row (256*2)
#define ZOFF ((unsigned)HWSZ * ROWB) // zero page offset from f2tb base

typedef __attribute__((ext_vector_type(8))) short short8v;  // 8 bf16 (4 VGPRs)
typedef __attribute__((ext_vector_type(4))) float f32x4;

__device__ __forceinline__ unsigned bf16rne(float f) {      // RNE f32->bf16 bits
  unsigned u = __float_as_uint(f);
  return (u + 0x7FFFu + ((u >> 16) & 1u)) >> 16;
}

// async global->LDS: LDS dest = wave-uniform base + lane*16 (linear), global src
// per-lane. UNSWIZZLED: patch rows pair up xx-consecutively, so each instr's 64
// lanes cover ONE contiguous 1KB run for interior pixels -> full TA lane-merge
// (the R9/R10 XOR-swizzled source permuted chunks and defeated the merge).
__device__ __forceinline__ void gload_lds16(const char* g, char* l) {
  __builtin_amdgcn_global_load_lds(
      (const __attribute__((address_space(1))) char*)g,
      (__attribute__((address_space(3))) char*)l, 16, 0, 0);
}

// ---------------- kernel 1: transposes + W-prep (fragment-major) ----------------
// y==0: f1 -> f1tb [pixel][256ch] bf16; blocks x<36 also pack W into Wf in MFMA
//   FRAGMENT-MAJOR order: Wf[((m*3+kt)*64 + lane)*8 + e] = bf16(W[r][c]),
//   r = m*16+(lane&15), c = kt*32+(lane>>4)*8+e  (zero-padded past 81).
// y==1: f2 -> f2tb same layout, + zero page
__global__ __launch_bounds__(256) void transpose_to_bf16(
    const float* __restrict__ f1, const float* __restrict__ f2,
    const float* __restrict__ w_dap, char* __restrict__ f2tb,
    char* __restrict__ f1tb, char* __restrict__ zpage,
    unsigned short* __restrict__ Wf) {
  __shared__ float tile[64][65];
  const float* src = (blockIdx.y == 0) ? f1 : f2;
  char* dst = (blockIdx.y == 0) ? f1tb : f2tb;

  const int tid = threadIdx.x;
  if (blockIdx.y == 0 && blockIdx.x == 0 && tid < 32) {   // zero the 512 B zero page
    float4 z = {0.f, 0.f, 0.f, 0.f};
    *(float4*)(zpage + tid * 16) = z;
  }
  if (blockIdx.y == 0 && blockIdx.x < 36) {   // W-prep: 9216 shorts over 36 blocks
    int gid = blockIdx.x * 256 + tid;
    int g = gid >> 9;                         // (m,kt) group 0..17
    int idx = gid & 511;
    int ln = idx >> 3, e = idx & 7;
    int m = g / 3, kt = g - m * 3;
    int r = m * 16 + (ln & 15);
    int c = kt * 32 + (ln >> 4) * 8 + e;
    float v = (r < DD2 && c < DD2) ? w_dap[r * DD2 + c] : 0.f;
    Wf[gid] = (unsigned short)bf16rne(v);
  }

  const int tiles_p = HWSZ / 64;              // 72
  const int bc = blockIdx.x / tiles_p;        // channel tile 0..3
  const int bp = blockIdx.x % tiles_p;        // pixel tile 0..71
  const int c0 = bc * 64, p0 = bp * 64;

#pragma unroll
  for (int k = 0; k < 16; k++) {
    int idx = k * 256 + tid;
    int cl = idx >> 6, pl = idx & 63;         // coalesced over pixels
    tile[cl][pl] = src[(size_t)(c0 + cl) * HWSZ + p0 + pl];
  }
  __syncthreads();
#pragma unroll
  for (int k = 0; k < 8; k++) {               // pack 2 channels -> 4 B stores
    int idx = k * 256 + tid;
    int pl = idx >> 5, cp = idx & 31;
    unsigned lo = bf16rne(tile[2 * cp][pl]);
    unsigned hi = bf16rne(tile[2 * cp + 1][pl]);
    *(unsigned*)(dst + (size_t)(p0 + pl) * ROWB + (size_t)c0 * 2 + cp * 4) =
        lo | (hi << 16);
  }
}

// ---------------- kernel 2: staged MFMA correlation + MFMA DAP, one block/pixel ----------------
__global__ __launch_bounds__(256, 3) void corr_main(
    const char* __restrict__ f2tb, const char* __restrict__ f1tb,
    const float* __restrict__ coords, const unsigned short* __restrict__ Wf,
    float* __restrict__ out) {
  __shared__ __align__(16) char patch[100 * ROWB];  // 51200 B, LINEAR layout
  __shared__ unsigned rowoff[100];            // source byte offset (ZOFF = zero page)
  __shared__ float dots[112];
  __shared__ __align__(16) unsigned short cb[96];   // bf16(corr), zero-padded

  const int p = blockIdx.x;                   // pixel h*W+w
  const int tid = threadIdx.x;

  const float cx = coords[p];
  const float cy = coords[HWSZ + p];
  const float fxf = floorf(cx), fyf = floorf(cy);
  const float fx = cx - fxf, fy = cy - fyf;   // fractional weights shared by all 81 offsets
  const int xb = (int)fxf - RRAD;
  const int yb = (int)fyf - RRAD;

  if (tid < 100) {
    int yy = tid / 10, xx = tid - yy * 10;
    int gy = yb + yy, gx = xb + xx;
    rowoff[tid] = (gx >= 0 && gx < WW && gy >= 0 && gy < HH)
                      ? (unsigned)(gy * WW + gx) * ROWB : ZOFF;
  }

  const int lane = tid & 63, wid = tid >> 6;
  const int hi = lane >> 4, lo = lane & 15;

  // B fragments: f1 vector (same for all 16 cols); k = hi*8 + j within ktile kt
  const char* f1b = f1tb + (size_t)p * ROWB + hi * 16;
  short8v bfrag[8];
#pragma unroll
  for (int kt = 0; kt < 8; kt++) bfrag[kt] = *(const short8v*)(f1b + kt * 64);

  __syncthreads();                            // rowoff ready

  // stage 100 rows via global_load_lds; 2 xx-consecutive rows per instr ->
  // contiguous 1KB source run for interior pixels. LDS dest linear.
  {
    const int sub = lane >> 5;                // which of the 2 rows in this instr
    const int col = (lane & 31) * 16;         // byte within row
    for (int s = wid; s < 50; s += 4) {
      const int r = 2 * s + sub;
      gload_lds16(f2tb + rowoff[r] + col, &patch[s * 1024]);
    }
  }
  __syncthreads();                            // drains vmcnt (staging complete)

  // 7 m-tiles of 16 patch rows; A-fragments from linear LDS (16-way bank
  // conflict on b128 reads, ~16 reads/wave -- measured tolerable in R7)
#pragma unroll
  for (int mi = 0; mi < 2; mi++) {
    const int m = wid + mi * 4;
    if (m < 7) {
      int row = m * 16 + lo;
      row = row > 99 ? 99 : row;              // tile-6 tail: dup row, discarded
      const char* rp = patch + row * ROWB + hi * 16;
      short8v a[8];
#pragma unroll
      for (int kt = 0; kt < 8; kt++)
        a[kt] = *(const short8v*)(rp + kt * 64);
      f32x4 acc = {0.f, 0.f, 0.f, 0.f};
#pragma unroll
      for (int kt = 0; kt < 8; kt++)
        acc = __builtin_amdgcn_mfma_f32_16x16x32_bf16(a[kt], bfrag[kt], acc, 0, 0, 0);
      // D: col = lo, row = hi*4 + j; keep col 0 only
      if (lo == 0) {
        const int rb = m * 16 + hi * 4;
        dots[rb + 0] = acc[0];
        dots[rb + 1] = acc[1];
        dots[rb + 2] = acc[2];
        dots[rb + 3] = acc[3];
      }
    }
  }
  __syncthreads();

  // 81 bilinear combines -> cb[96] bf16 (zero-padded)
  if (tid < 96) {
    float c = 0.f;
    if (tid < DD2) {
      const int i = tid / DD, j = tid - i * DD;
      const float d00 = dots[j * PP + i];
      const float d01 = dots[j * PP + i + 1];
      const float d10 = dots[(j + 1) * PP + i];
      const float d11 = dots[(j + 1) * PP + i + 1];
      c = ((1.f - fy) * ((1.f - fx) * d00 + fx * d01) +
           fy * ((1.f - fx) * d10 + fx * d11)) * 0.0625f;   // 1/sqrt(256)
    }
    cb[tid] = (unsigned short)bf16rne(c);
  }
  __syncthreads();

  // DAP via MFMA: out96 = W(96x96) . cb. A-fragments from Wf (fragment-major,
  // 1KB contiguous per wave-load, L1-resident). Store col 0.
  short8v bq[3];
#pragma unroll
  for (int kt = 0; kt < 3; kt++)
    bq[kt] = *(const short8v*)&cb[kt * 32 + hi * 8];
#pragma unroll
  for (int mi = 0; mi < 2; mi++) {
    const int m = wid + mi * 4;
    if (m < 6) {
      const unsigned short* wr = Wf + ((size_t)(m * 3) * 64 + lane) * 8;
      f32x4 acc = {0.f, 0.f, 0.f, 0.f};
#pragma unroll
      for (int kt = 0; kt < 3; kt++) {
        short8v aw = *(const short8v*)(wr + (size_t)kt * 512);
        acc = __builtin_amdgcn_mfma_f32_16x16x32_bf16(aw, bq[kt], acc, 0, 0, 0);
      }
      if (lo == 0) {
#pragma unroll
        for (int j = 0; j < 4; j++) {
          const int o = m * 16 + hi * 4 + j;
          if (o < DD2) out[(size_t)o * HWSZ + p] = acc[j];
        }
      }
    }
  }
}

extern "C" void kernel_launch(void* const* d_in, const int* in_sizes, int n_in,
                              void* d_out, int out_size, void* d_ws, size_t ws_size,
                              hipStream_t stream) {
  const float* f1     = (const float*)d_in[0];
  const float* f2     = (const float*)d_in[1];
  const float* coords = (const float*)d_in[2];
  const float* w_dap  = (const float*)d_in[3];
  float* out = (float*)d_out;

  // ws layout: [f2tb: HWSZ*512][zpage: 512][f1tb: HWSZ*512][Wf: 9216*2]
  char* f2tb  = (char*)d_ws;
  char* zpage = f2tb + (size_t)HWSZ * ROWB;
  char* f1tb  = zpage + 512;
  unsigned short* Wf = (unsigned short*)(f1tb + (size_t)HWSZ * ROWB);

  dim3 tgrid((CC / 64) * (HWSZ / 64), 2);
  transpose_to_bf16<<<tgrid, 256, 0, stream>>>(f1, f2, w_dap, f2tb, f1tb, zpage, Wf);

  corr_main<<<dim3(HWSZ), 256, 0, stream>>>(f2tb, f1tb, coords, Wf, out);
}

// Round 12
// 35.624 us; speedup vs baseline: 1.1564x; 1.1564x over previous
//
#include <hip/hip_runtime.h>

#define HH   48
#define WW   96
#define CC   256
#define RRAD 4
#define DD   9
#define DD2  81
#define PP   10
#define HWSZ (HH * WW)              // 4608
#define ROWB 512                    // bytes per bf16 channel row (256*2)
#define ZOFF ((unsigned)HWSZ * ROWB) // zero page offset from f2tb base

typedef __attribute__((ext_vector_type(8))) short short8v;  // 8 bf16 (4 VGPRs)
typedef __attribute__((ext_vector_type(4))) float f32x4;

__device__ __forceinline__ unsigned bf16rne(float f) {      // RNE f32->bf16 bits
  unsigned u = __float_as_uint(f);
  return (u + 0x7FFFu + ((u >> 16) & 1u)) >> 16;
}

__device__ __forceinline__ void gload_lds16(const char* g, char* l) {
  __builtin_amdgcn_global_load_lds(
      (const __attribute__((address_space(1))) char*)g,
      (__attribute__((address_space(3))) char*)l, 16, 0, 0);
}

// ---------------- kernel 1: transposes + W-prep (fragment-major) ----------------
__global__ __launch_bounds__(256) void transpose_to_bf16(
    const float* __restrict__ f1, const float* __restrict__ f2,
    const float* __restrict__ w_dap, char* __restrict__ f2tb,
    char* __restrict__ f1tb, char* __restrict__ zpage,
    unsigned short* __restrict__ Wf) {
  __shared__ float tile[64][65];
  const float* src = (blockIdx.y == 0) ? f1 : f2;
  char* dst = (blockIdx.y == 0) ? f1tb : f2tb;

  const int tid = threadIdx.x;
  if (blockIdx.y == 0 && blockIdx.x == 0 && tid < 32) {   // zero the 512 B zero page
    float4 z = {0.f, 0.f, 0.f, 0.f};
    *(float4*)(zpage + tid * 16) = z;
  }
  if (blockIdx.y == 0 && blockIdx.x < 36) {   // W-prep: 9216 shorts over 36 blocks
    int gid = blockIdx.x * 256 + tid;
    int g = gid >> 9;                         // (m,kt) group 0..17
    int idx = gid & 511;
    int ln = idx >> 3, e = idx & 7;
    int m = g / 3, kt = g - m * 3;
    int r = m * 16 + (ln & 15);
    int c = kt * 32 + (ln >> 4) * 8 + e;
    float v = (r < DD2 && c < DD2) ? w_dap[r * DD2 + c] : 0.f;
    Wf[gid] = (unsigned short)bf16rne(v);
  }

  const int tiles_p = HWSZ / 64;              // 72
  const int bc = blockIdx.x / tiles_p;        // channel tile 0..3
  const int bp = blockIdx.x % tiles_p;        // pixel tile 0..71
  const int c0 = bc * 64, p0 = bp * 64;

#pragma unroll
  for (int k = 0; k < 16; k++) {
    int idx = k * 256 + tid;
    int cl = idx >> 6, pl = idx & 63;         // coalesced over pixels
    tile[cl][pl] = src[(size_t)(c0 + cl) * HWSZ + p0 + pl];
  }
  __syncthreads();
#pragma unroll
  for (int k = 0; k < 8; k++) {               // pack 2 channels -> 4 B stores
    int idx = k * 256 + tid;
    int pl = idx >> 5, cp = idx & 31;
    unsigned lo = bf16rne(tile[2 * cp][pl]);
    unsigned hi = bf16rne(tile[2 * cp + 1][pl]);
    *(unsigned*)(dst + (size_t)(p0 + pl) * ROWB + (size_t)c0 * 2 + cp * 4) =
        lo | (hi << 16);
  }
}

// ---------------- kernel 2: per-wave-owned staging, barrier-free corr + MFMA DAP ----------------
// Wave w stages AND computes tiles {w, w+4}: staging->MFMA sync is per-wave
// counted vmcnt (no block barrier, no full drain). Only 2 raw s_barriers
// (dots, cb) with lgkmcnt-only. Swizzle kept (R11 proved it's +5us).
__global__ __launch_bounds__(256, 3) void corr_main(
    const char* __restrict__ f2tb, const char* __restrict__ f1tb,
    const float* __restrict__ coords, const unsigned short* __restrict__ Wf,
    float* __restrict__ out) {
  __shared__ __align__(16) char patch[100 * ROWB];  // 51200 B
  __shared__ __align__(16) char f1buf[1024];        // staged f1 row (lower 512B real)
  __shared__ float dots[112];
  __shared__ __align__(16) unsigned short cb[96];

  const int p = blockIdx.x;
  const int tid = threadIdx.x;
  const int lane = tid & 63, wid = tid >> 6;
  const int hi = lane >> 4, lo = lane & 15;
  const int sub = lane >> 5;                  // row within a staging pair
  const char* zp = f2tb + ZOFF;

  const float cx = coords[p];
  const float cy = coords[HWSZ + p];
  const float fxf = floorf(cx), fyf = floorf(cy);
  const float fx = cx - fxf, fy = cy - fyf;
  const int xb = (int)fxf - RRAD;
  const int yb = (int)fyf - RRAD;

  // ---- staging (per-wave issue stream; order defines vmcnt bookkeeping) ----
  // [f1:1][tileA:8][tileB:8|2|0]  (w2 tileB=rows 96-99 only; w3 has no tileB)
  {
    const char* fs = (lane < 32) ? (f1tb + (size_t)p * ROWB + (lane & 31) * 16)
                                 : (zp + (lane & 31) * 16);
    gload_lds16(fs, f1buf);
  }
#pragma unroll
  for (int half = 0; half < 2; half++) {
    const int ti = wid + half * 4;            // 0..7
    if (ti < 7) {
#pragma unroll
      for (int rp = 0; rp < 8; rp++) {
        const int base = ti * 16 + rp * 2;
        if (base < 100) {                     // skip dummy rows 100+
          const int r = base + sub;
          const int yy = (r * 205) >> 11;     // r/10 (exact for r<112)
          const int xx = r - yy * 10;
          const int gy = yb + yy, gx = xb + xx;
          const unsigned ro = (gx >= 0 && gx < WW && gy >= 0 && gy < HH)
                                  ? (unsigned)(gy * WW + gx) * ROWB : ZOFF;
          const char* src =
              f2tb + ro + (((lane & 31) * 16) ^ ((r & 7) << 4));
          gload_lds16(src, &patch[base * ROWB]);
        }
      }
    }
  }

  // ---- per-wave counted wait for own tile A (f1 retires with it) ----
  if (wid == 3)      asm volatile("s_waitcnt vmcnt(0)" ::: "memory");
  else if (wid == 2) asm volatile("s_waitcnt vmcnt(2)" ::: "memory");
  else               asm volatile("s_waitcnt vmcnt(8)" ::: "memory");
  __builtin_amdgcn_sched_barrier(0);

  // B fragments from LDS f1buf (broadcast reads, lgkm domain)
  short8v bfrag[8];
#pragma unroll
  for (int kt = 0; kt < 8; kt++)
    bfrag[kt] = *(const short8v*)(f1buf + hi * 16 + kt * 64);

  // ---- tile A ----
  {
    const int m = wid;
    int row = m * 16 + lo;
    const char* rp2 = patch + row * ROWB;
    const int swz = (row & 7) << 4;
    short8v a[8];
#pragma unroll
    for (int kt = 0; kt < 8; kt++)
      a[kt] = *(const short8v*)(rp2 + ((hi * 16 + kt * 64) ^ swz));
    f32x4 acc = {0.f, 0.f, 0.f, 0.f};
#pragma unroll
    for (int kt = 0; kt < 8; kt++)
      acc = __builtin_amdgcn_mfma_f32_16x16x32_bf16(a[kt], bfrag[kt], acc, 0, 0, 0);
    if (lo == 0) {
      const int rb = m * 16 + hi * 4;
      dots[rb + 0] = acc[0]; dots[rb + 1] = acc[1];
      dots[rb + 2] = acc[2]; dots[rb + 3] = acc[3];
    }
  }

  // ---- tile B (waves 0-2), after own vmcnt(0) ----
  if (wid < 3) {
    asm volatile("s_waitcnt vmcnt(0)" ::: "memory");
    __builtin_amdgcn_sched_barrier(0);
    const int m = wid + 4;
    int row = m * 16 + lo;
    row = row > 99 ? 99 : row;                // tile 6 tail: dup row, dots discarded
    const char* rp2 = patch + row * ROWB;
    const int swz = (row & 7) << 4;
    short8v a[8];
#pragma unroll
    for (int kt = 0; kt < 8; kt++)
      a[kt] = *(const short8v*)(rp2 + ((hi * 16 + kt * 64) ^ swz));
    f32x4 acc = {0.f, 0.f, 0.f, 0.f};
#pragma unroll
    for (int kt = 0; kt < 8; kt++)
      acc = __builtin_amdgcn_mfma_f32_16x16x32_bf16(a[kt], bfrag[kt], acc, 0, 0, 0);
    if (lo == 0) {
      const int rb = m * 16 + hi * 4;
      dots[rb + 0] = acc[0]; dots[rb + 1] = acc[1];
      dots[rb + 2] = acc[2]; dots[rb + 3] = acc[3];
    }
  }

  // ---- dots ready: raw barrier (lgkm only — no vmcnt drain) ----
  asm volatile("s_waitcnt lgkmcnt(0)" ::: "memory");
  __builtin_amdgcn_s_barrier();

  // 81 bilinear combines -> cb[96] bf16 (zero-padded)
  if (tid < 96) {
    float c = 0.f;
    if (tid < DD2) {
      const int i = tid / DD, j = tid - i * DD;
      const float d00 = dots[j * PP + i];
      const float d01 = dots[j * PP + i + 1];
      const float d10 = dots[(j + 1) * PP + i];
      const float d11 = dots[(j + 1) * PP + i + 1];
      c = ((1.f - fy) * ((1.f - fx) * d00 + fx * d01) +
           fy * ((1.f - fx) * d10 + fx * d11)) * 0.0625f;   // 1/sqrt(256)
    }
    cb[tid] = (unsigned short)bf16rne(c);
  }
  asm volatile("s_waitcnt lgkmcnt(0)" ::: "memory");
  __builtin_amdgcn_s_barrier();

  // ---- DAP via MFMA: out96 = W(96x96) . cb (Wf fragment-major, L1-resident) ----
  short8v bq[3];
#pragma unroll
  for (int kt = 0; kt < 3; kt++)
    bq[kt] = *(const short8v*)&cb[kt * 32 + hi * 8];
#pragma unroll
  for (int mi = 0; mi < 2; mi++) {
    const int m = wid + mi * 4;
    if (m < 6) {
      const unsigned short* wr = Wf + ((size_t)(m * 3) * 64 + lane) * 8;
      f32x4 acc = {0.f, 0.f, 0.f, 0.f};
#pragma unroll
      for (int kt = 0; kt < 3; kt++) {
        short8v aw = *(const short8v*)(wr + (size_t)kt * 512);
        acc = __builtin_amdgcn_mfma_f32_16x16x32_bf16(aw, bq[kt], acc, 0, 0, 0);
      }
      if (lo == 0) {
#pragma unroll
        for (int j = 0; j < 4; j++) {
          const int o = m * 16 + hi * 4 + j;
          if (o < DD2) out[(size_t)o * HWSZ + p] = acc[j];
        }
      }
    }
  }
}

extern "C" void kernel_launch(void* const* d_in, const int* in_sizes, int n_in,
                              void* d_out, int out_size, void* d_ws, size_t ws_size,
                              hipStream_t stream) {
  const float* f1     = (const float*)d_in[0];
  const float* f2     = (const float*)d_in[1];
  const float* coords = (const float*)d_in[2];
  const float* w_dap  = (const float*)d_in[3];
  float* out = (float*)d_out;

  // ws layout: [f2tb: HWSZ*512][zpage: 512][f1tb: HWSZ*512][Wf: 9216*2]
  char* f2tb  = (char*)d_ws;
  char* zpage = f2tb + (size_t)HWSZ * ROWB;
  char* f1tb  = zpage + 512;
  unsigned short* Wf = (unsigned short*)(f1tb + (size_t)HWSZ * ROWB);

  dim3 tgrid((CC / 64) * (HWSZ / 64), 2);
  transpose_to_bf16<<<tgrid, 256, 0, stream>>>(f1, f2, w_dap, f2tb, f1tb, zpage, Wf);

  corr_main<<<dim3(HWSZ), 256, 0, stream>>>(f2tb, f1tb, coords, Wf, out);
}

// Round 13
// 33.529 us; speedup vs baseline: 1.2286x; 1.0625x over previous
//
#include <hip/hip_runtime.h>

#define HH   48
#define WW   96
#define CC   256
#define RRAD 4
#define DD   9
#define DD2  81
#define PP   10
#define HWSZ (HH * WW)              // 4608
#define ROWB 512                    // bytes per bf16 channel row (256*2)
#define ZOFF ((unsigned)HWSZ * ROWB) // zero page offset from f2tb base

typedef __attribute__((ext_vector_type(8))) short short8v;  // 8 bf16 (4 VGPRs)
typedef __attribute__((ext_vector_type(4))) float f32x4;

__device__ __forceinline__ unsigned bf16rne(float f) {      // RNE f32->bf16 bits
  unsigned u = __float_as_uint(f);
  return (u + 0x7FFFu + ((u >> 16) & 1u)) >> 16;
}

__device__ __forceinline__ void gload_lds16(const char* g, char* l) {
  __builtin_amdgcn_global_load_lds(
      (const __attribute__((address_space(1))) char*)g,
      (__attribute__((address_space(3))) char*)l, 16, 0, 0);
}

// ---------------- kernel 1: transposes + W-prep (fragment-major) ----------------
__global__ __launch_bounds__(256) void transpose_to_bf16(
    const float* __restrict__ f1, const float* __restrict__ f2,
    const float* __restrict__ w_dap, char* __restrict__ f2tb,
    char* __restrict__ f1tb, char* __restrict__ zpage,
    unsigned short* __restrict__ Wf) {
  __shared__ float tile[64][65];
  const float* src = (blockIdx.y == 0) ? f1 : f2;
  char* dst = (blockIdx.y == 0) ? f1tb : f2tb;

  const int tid = threadIdx.x;
  if (blockIdx.y == 0 && blockIdx.x == 0 && tid < 32) {   // zero the 512 B zero page
    float4 z = {0.f, 0.f, 0.f, 0.f};
    *(float4*)(zpage + tid * 16) = z;
  }
  if (blockIdx.y == 0 && blockIdx.x < 36) {   // W-prep: 9216 shorts over 36 blocks
    int gid = blockIdx.x * 256 + tid;
    int g = gid >> 9;                         // (m,kt) group 0..17
    int idx = gid & 511;
    int ln = idx >> 3, e = idx & 7;
    int m = g / 3, kt = g - m * 3;
    int r = m * 16 + (ln & 15);
    int c = kt * 32 + (ln >> 4) * 8 + e;
    float v = (r < DD2 && c < DD2) ? w_dap[r * DD2 + c] : 0.f;
    Wf[gid] = (unsigned short)bf16rne(v);
  }

  const int tiles_p = HWSZ / 64;              // 72
  const int bc = blockIdx.x / tiles_p;        // channel tile 0..3
  const int bp = blockIdx.x % tiles_p;        // pixel tile 0..71
  const int c0 = bc * 64, p0 = bp * 64;

#pragma unroll
  for (int k = 0; k < 16; k++) {
    int idx = k * 256 + tid;
    int cl = idx >> 6, pl = idx & 63;         // coalesced over pixels
    tile[cl][pl] = src[(size_t)(c0 + cl) * HWSZ + p0 + pl];
  }
  __syncthreads();
#pragma unroll
  for (int k = 0; k < 8; k++) {               // pack 2 channels -> 4 B stores
    int idx = k * 256 + tid;
    int pl = idx >> 5, cp = idx & 31;
    unsigned lo = bf16rne(tile[2 * cp][pl]);
    unsigned hi = bf16rne(tile[2 * cp + 1][pl]);
    *(unsigned*)(dst + (size_t)(p0 + pl) * ROWB + (size_t)c0 * 2 + cp * 4) =
        lo | (hi << 16);
  }
}

// ---------------- kernel 2: corr only (R12 staging core) -> cbg[p][96] bf16 ----------------
__global__ __launch_bounds__(256, 3) void corr_main(
    const char* __restrict__ f2tb, const char* __restrict__ f1tb,
    const float* __restrict__ coords, unsigned short* __restrict__ cbg) {
  __shared__ __align__(16) char patch[100 * ROWB];  // 51200 B
  __shared__ __align__(16) char f1buf[1024];        // staged f1 row (lower 512B real)
  __shared__ float dots[112];

  const int p = blockIdx.x;
  const int tid = threadIdx.x;
  const int lane = tid & 63, wid = tid >> 6;
  const int hi = lane >> 4, lo = lane & 15;
  const int sub = lane >> 5;                  // row within a staging pair
  const char* zp = f2tb + ZOFF;

  const float cx = coords[p];
  const float cy = coords[HWSZ + p];
  const float fxf = floorf(cx), fyf = floorf(cy);
  const float fx = cx - fxf, fy = cy - fyf;
  const int xb = (int)fxf - RRAD;
  const int yb = (int)fyf - RRAD;

  // ---- staging (per-wave issue stream; order defines vmcnt bookkeeping) ----
  // [f1:1][tileA:8][tileB:8|2|0]  (w2 tileB=rows 96-99 only; w3 has no tileB)
  {
    const char* fs = (lane < 32) ? (f1tb + (size_t)p * ROWB + (lane & 31) * 16)
                                 : (zp + (lane & 31) * 16);
    gload_lds16(fs, f1buf);
  }
#pragma unroll
  for (int half = 0; half < 2; half++) {
    const int ti = wid + half * 4;            // 0..7
    if (ti < 7) {
#pragma unroll
      for (int rp = 0; rp < 8; rp++) {
        const int base = ti * 16 + rp * 2;
        if (base < 100) {                     // skip dummy rows 100+
          const int r = base + sub;
          const int yy = (r * 205) >> 11;     // r/10 (exact for r<112)
          const int xx = r - yy * 10;
          const int gy = yb + yy, gx = xb + xx;
          const unsigned ro = (gx >= 0 && gx < WW && gy >= 0 && gy < HH)
                                  ? (unsigned)(gy * WW + gx) * ROWB : ZOFF;
          const char* src =
              f2tb + ro + (((lane & 31) * 16) ^ ((r & 7) << 4));
          gload_lds16(src, &patch[base * ROWB]);
        }
      }
    }
  }

  // ---- per-wave counted wait for own tile A (f1 retires with it) ----
  if (wid == 3)      asm volatile("s_waitcnt vmcnt(0)" ::: "memory");
  else if (wid == 2) asm volatile("s_waitcnt vmcnt(2)" ::: "memory");
  else               asm volatile("s_waitcnt vmcnt(8)" ::: "memory");
  __builtin_amdgcn_sched_barrier(0);

  // B fragments from LDS f1buf (broadcast reads, lgkm domain)
  short8v bfrag[8];
#pragma unroll
  for (int kt = 0; kt < 8; kt++)
    bfrag[kt] = *(const short8v*)(f1buf + hi * 16 + kt * 64);

  // ---- tile A ----
  {
    const int m = wid;
    int row = m * 16 + lo;
    const char* rp2 = patch + row * ROWB;
    const int swz = (row & 7) << 4;
    short8v a[8];
#pragma unroll
    for (int kt = 0; kt < 8; kt++)
      a[kt] = *(const short8v*)(rp2 + ((hi * 16 + kt * 64) ^ swz));
    f32x4 acc = {0.f, 0.f, 0.f, 0.f};
#pragma unroll
    for (int kt = 0; kt < 8; kt++)
      acc = __builtin_amdgcn_mfma_f32_16x16x32_bf16(a[kt], bfrag[kt], acc, 0, 0, 0);
    if (lo == 0) {
      const int rb = m * 16 + hi * 4;
      dots[rb + 0] = acc[0]; dots[rb + 1] = acc[1];
      dots[rb + 2] = acc[2]; dots[rb + 3] = acc[3];
    }
  }

  // ---- tile B (waves 0-2), after own vmcnt(0) ----
  if (wid < 3) {
    asm volatile("s_waitcnt vmcnt(0)" ::: "memory");
    __builtin_amdgcn_sched_barrier(0);
    const int m = wid + 4;
    int row = m * 16 + lo;
    row = row > 99 ? 99 : row;                // tile 6 tail: dup row, dots discarded
    const char* rp2 = patch + row * ROWB;
    const int swz = (row & 7) << 4;
    short8v a[8];
#pragma unroll
    for (int kt = 0; kt < 8; kt++)
      a[kt] = *(const short8v*)(rp2 + ((hi * 16 + kt * 64) ^ swz));
    f32x4 acc = {0.f, 0.f, 0.f, 0.f};
#pragma unroll
    for (int kt = 0; kt < 8; kt++)
      acc = __builtin_amdgcn_mfma_f32_16x16x32_bf16(a[kt], bfrag[kt], acc, 0, 0, 0);
    if (lo == 0) {
      const int rb = m * 16 + hi * 4;
      dots[rb + 0] = acc[0]; dots[rb + 1] = acc[1];
      dots[rb + 2] = acc[2]; dots[rb + 3] = acc[3];
    }
  }

  // ---- dots ready: raw barrier (lgkm only — no vmcnt drain) ----
  asm volatile("s_waitcnt lgkmcnt(0)" ::: "memory");
  __builtin_amdgcn_s_barrier();

  // 81 bilinear combines -> cbg[p][96] bf16 (192 B contiguous per pixel)
  if (tid < 96) {
    float c = 0.f;
    if (tid < DD2) {
      const int i = tid / DD, j = tid - i * DD;
      const float d00 = dots[j * PP + i];
      const float d01 = dots[j * PP + i + 1];
      const float d10 = dots[(j + 1) * PP + i];
      const float d11 = dots[(j + 1) * PP + i + 1];
      c = ((1.f - fy) * ((1.f - fx) * d00 + fx * d01) +
           fy * ((1.f - fx) * d10 + fx * d11)) * 0.0625f;   // 1/sqrt(256)
    }
    cbg[(size_t)p * 96 + tid] = (unsigned short)bf16rne(c);
  }
}

// ---------------- kernel 3: DAP as batched GEMM  out[96x4608] = W(96x96).CB ----------------
// 288 blocks x 1 wave; each computes a 96x16 C-tile (16 pixels) with 18 MFMAs.
// A = Wf fragment-major (1KB contiguous per load, L2-hot); B = cbg per-lane 16B.
__global__ __launch_bounds__(64) void dap_gemm(
    const unsigned short* __restrict__ cbg, const unsigned short* __restrict__ Wf,
    float* __restrict__ out) {
  const int lane = threadIdx.x;
  const int hi = lane >> 4, lo = lane & 15;
  const int p0 = blockIdx.x * 16;

  // B-fragments: pixel p0+lo, k = kt*32 + hi*8 + e
  short8v bq[3];
#pragma unroll
  for (int kt = 0; kt < 3; kt++)
    bq[kt] = *(const short8v*)(cbg + (size_t)(p0 + lo) * 96 + kt * 32 + hi * 8);

  f32x4 acc[6];
#pragma unroll
  for (int m = 0; m < 6; m++) acc[m] = (f32x4){0.f, 0.f, 0.f, 0.f};

#pragma unroll
  for (int m = 0; m < 6; m++) {
#pragma unroll
    for (int kt = 0; kt < 3; kt++) {
      short8v aw = *(const short8v*)(Wf + ((size_t)(m * 3 + kt) * 64 + lane) * 8);
      acc[m] = __builtin_amdgcn_mfma_f32_16x16x32_bf16(aw, bq[kt], acc[m], 0, 0, 0);
    }
  }

  // C: row(o) = m*16 + hi*4 + j, col(pixel) = lo; 64 B contiguous per (m,j)
#pragma unroll
  for (int m = 0; m < 6; m++) {
#pragma unroll
    for (int j = 0; j < 4; j++) {
      const int o = m * 16 + hi * 4 + j;
      if (o < DD2) out[(size_t)o * HWSZ + p0 + lo] = acc[m][j];
    }
  }
}

extern "C" void kernel_launch(void* const* d_in, const int* in_sizes, int n_in,
                              void* d_out, int out_size, void* d_ws, size_t ws_size,
                              hipStream_t stream) {
  const float* f1     = (const float*)d_in[0];
  const float* f2     = (const float*)d_in[1];
  const float* coords = (const float*)d_in[2];
  const float* w_dap  = (const float*)d_in[3];
  float* out = (float*)d_out;

  // ws layout: [f2tb: HWSZ*512][zpage: 512][f1tb: HWSZ*512][Wf: 9216*2][cbg: HWSZ*96*2]
  char* f2tb  = (char*)d_ws;
  char* zpage = f2tb + (size_t)HWSZ * ROWB;
  char* f1tb  = zpage + 512;
  unsigned short* Wf  = (unsigned short*)(f1tb + (size_t)HWSZ * ROWB);
  unsigned short* cbg = Wf + 9216;

  dim3 tgrid((CC / 64) * (HWSZ / 64), 2);
  transpose_to_bf16<<<tgrid, 256, 0, stream>>>(f1, f2, w_dap, f2tb, f1tb, zpage, Wf);

  corr_main<<<dim3(HWSZ), 256, 0, stream>>>(f2tb, f1tb, coords, cbg);

  dap_gemm<<<dim3(HWSZ / 16), 64, 0, stream>>>(cbg, Wf, out);
}